// Round 1
// 1154.290 us; speedup vs baseline: 1.3396x; 1.3396x over previous
//
#include <hip/hip_runtime.h>
#include <math.h>

// Problem constants
#define BB 16
#define LL 5000
#define DIN 12
#define HH 256
#define NN 32
#define NLAYER 4
#define LC 125               // chunk length
#define NCH 40               // chunks per batch row (40*125 = 5000)
#define COLS (BB*NCH)        // 640 chunk-columns; col = b*40+c, row = col*125+t
#define NROWS (BB*LL)        // 80000 token rows
#define KU 192               // Ubig inner dim: 128 (tau, padded) + 64 (state re/im)

typedef __attribute__((ext_vector_type(8))) _Float16 f16x8;
typedef __attribute__((ext_vector_type(4))) float f32x4;

// fast tanh-GELU (matches jax.nn.gelu approximate): a*sigmoid(2*inner)
__device__ __forceinline__ float fast_gelu(float a) {
  float z = fmaf(0.0713548163f * a, a * a, 1.5957691216f * a);
  float e = __expf(-z);
  return a * __builtin_amdgcn_rcpf(1.0f + e);
}

__device__ __forceinline__ unsigned pk2h(float a, float b) {
  union { _Float16 h[2]; unsigned u; } x;
  x.h[0] = (_Float16)a; x.h[1] = (_Float16)b;
  return x.u;
}

// ---------------------------------------------------------------------------
// Per-layer precompute of the chunked-convolution operators (fp16):
//   Tc[h][t=0..127][k=0..191] : k<128 -> Toeplitz K[t-k] (+D on diag); k>=128 ->
//                               boundary Bnd[t][n2] = {Re, -Im}(Ct2_n * w_n^{t+1})
//   V[h][n2=0..63][tau=0..127]: {Re,Im}(w_n^{124-tau})   (chunk-state operator)
//   WLc[h][n2]                : w^125 (combine step)
// Rows t>=125 and cols tau>=125 are zeroed (padding).
// ---------------------------------------------------------------------------
__global__ __launch_bounds__(128) void paramT_kernel(
    const float* __restrict__ log_dt, const float* __restrict__ logA_re,
    const float* __restrict__ A_im, const float* __restrict__ Cp,
    const float* __restrict__ Dv, int l,
    _Float16* __restrict__ Tc, _Float16* __restrict__ V, float* __restrict__ WLc) {
  int h = blockIdx.x;
  int t = threadIdx.x;
  __shared__ float s_are[NN], s_aim[NN], s_cre[NN], s_cim[NN];
  __shared__ float s_K[LC];
  if (t < NN) {
    int n = t;
    int idx = (l * HH + h) * NN + n;
    float dt = expf(log_dt[l * HH + h]);
    float Are = -expf(logA_re[idx]);
    float Aim = A_im[idx];
    float are = Are * dt, aim = Aim * dt;
    float e = expf(are);
    float wre = e * cosf(aim), wim = e * sinf(aim);
    float cr = Cp[2 * idx], ci = Cp[2 * idx + 1];
    float nre = wre - 1.0f, nim = wim;
    float tre = cr * nre - ci * nim;
    float tim = cr * nim + ci * nre;
    float inv = 1.0f / (Are * Are + Aim * Aim);
    s_are[n] = are; s_aim[n] = aim;
    s_cre[n] = 2.0f * (tre * Are + tim * Aim) * inv;
    s_cim[n] = 2.0f * (tim * Are - tre * Aim) * inv;
    float eL = expf(125.0f * are);
    float ang = 125.0f * aim;
    WLc[h * 64 + 2 * n] = eL * cosf(ang);
    WLc[h * 64 + 2 * n + 1] = eL * sinf(ang);
  }
  __syncthreads();
  if (t < LC) {
    float ksum = 0.0f;
    unsigned* brow = (unsigned*)(Tc + ((size_t)h * 128 + t) * KU + 128);
    for (int n = 0; n < NN; n++) {
      float are = s_are[n], aim = s_aim[n];
      float cre = s_cre[n], cim = s_cim[n];
      float ft = (float)t;
      float E = expf(are * ft);
      float a = aim * ft;
      float wtre = E * cosf(a), wtim = E * sinf(a);        // w^t
      ksum = fmaf(cre, wtre, ksum);
      ksum = fmaf(-cim, wtim, ksum);
      float ew = expf(are);
      float wre = ew * cosf(aim), wim = ew * sinf(aim);    // w
      float wpre = wtre * wre - wtim * wim;                // w^{t+1}
      float wpim = wtre * wim + wtim * wre;
      float bre = cre * wpre - cim * wpim;                 // Re(Ct2*w^{t+1})
      float bim = -(cre * wpim + cim * wpre);              // -Im(Ct2*w^{t+1})
      brow[n] = pk2h(bre, bim);
      float fk = (float)(124 - t);
      float E2 = expf(are * fk);
      float a2 = aim * fk;
      V[((size_t)h * 64 + 2 * n) * 128 + t] = (_Float16)(E2 * cosf(a2));
      V[((size_t)h * 64 + 2 * n + 1) * 128 + t] = (_Float16)(E2 * sinf(a2));
    }
    s_K[t] = ksum;
  } else {
    // zero pad columns tau=125..127 of V and Bnd rows t=125..127
    for (int n2 = 0; n2 < 64; n2++) V[((size_t)h * 64 + n2) * 128 + t] = (_Float16)0.0f;
    unsigned* brow = (unsigned*)(Tc + ((size_t)h * 128 + t) * KU + 128);
    for (int q = 0; q < 32; q++) brow[q] = 0u;
  }
  __syncthreads();
  // Toeplitz rows (tau part), D folded into diagonal
  float D = Dv[l * HH + h];
  unsigned* row = (unsigned*)(Tc + ((size_t)h * 128 + t) * KU);
  for (int q = 0; q < 64; q++) {  // tau = 2q, 2q+1
    float v0 = 0.0f, v1 = 0.0f;
    if (t < LC) {
      int d0 = t - 2 * q;
      int d1 = d0 - 1;
      if (d0 >= 0) v0 = s_K[d0] + (d0 == 0 ? D : 0.0f);
      if (d1 >= 0) v1 = s_K[d1] + (d1 == 0 ? D : 0.0f);
    }
    row[q] = pk2h(v0, v1);
  }
}

// ---------------------------------------------------------------------------
// W_glu transpose+cast to fp16: Wt[l][col(512)][k(256)]
// ---------------------------------------------------------------------------
__global__ __launch_bounds__(256) void wt_kernel(
    const float* __restrict__ W, _Float16* __restrict__ Wt) {
  int gid = blockIdx.x * 256 + threadIdx.x;   // NLAYER*512 = 2048
  int l = gid >> 9, col = gid & 511;
  const float* w = W + (size_t)l * HH * 512 + col;
  _Float16* o = Wt + (size_t)gid * HH;
  for (int k = 0; k < HH; k++) o[k] = (_Float16)(w[(size_t)k * 512]);
}

// ---------------------------------------------------------------------------
// Input projection: stream = x @ W_in + b_in   (80000x12 @ 12x256)
// ---------------------------------------------------------------------------
__global__ __launch_bounds__(256) void proj_kernel(
    const float* __restrict__ x, const float* __restrict__ Win,
    const float* __restrict__ bin, float* __restrict__ X) {
  int h = threadIdx.x;
  float w[DIN];
#pragma unroll
  for (int k = 0; k < DIN; k++) w[k] = Win[k * HH + h];
  float bias = bin[h];
  for (int row = blockIdx.x; row < NROWS; row += gridDim.x) {
    float acc = bias;
#pragma unroll
    for (int k = 0; k < DIN; k++) acc = fmaf(x[row * DIN + k], w[k], acc);
    X[(size_t)row * HH + h] = acc;
  }
}

// ---------------------------------------------------------------------------
// Plain LayerNorm (final LN): one row per wave.
// ---------------------------------------------------------------------------
__global__ __launch_bounds__(256) void ln_kernel(
    const float* __restrict__ in, float* __restrict__ out,
    const float* __restrict__ g, const float* __restrict__ b) {
  int wave = threadIdx.x >> 6, lane = threadIdx.x & 63;
  int row = blockIdx.x * 4 + wave;
  const float4 v = ((const float4*)(in + (size_t)row * HH))[lane];
  float s = v.x + v.y + v.z + v.w;
  float q = v.x * v.x + v.y * v.y + v.z * v.z + v.w * v.w;
#pragma unroll
  for (int m = 1; m < 64; m <<= 1) { s += __shfl_xor(s, m); q += __shfl_xor(q, m); }
  float mean = s * (1.0f / HH);
  float var = q * (1.0f / HH) - mean * mean;
  float rstd = rsqrtf(var + 1e-5f);
  float4 gg = ((const float4*)g)[lane];
  float4 bb = ((const float4*)b)[lane];
  float4 o;
  o.x = (v.x - mean) * rstd * gg.x + bb.x;
  o.y = (v.y - mean) * rstd * gg.y + bb.y;
  o.z = (v.z - mean) * rstd * gg.z + bb.z;
  o.w = (v.w - mean) * rstd * gg.w + bb.w;
  ((float4*)(out + (size_t)row * HH))[lane] = o;
}

// ---------------------------------------------------------------------------
// Per-layer LN (in place on stream) fused with transposed fp16 export:
// U[h][col][tau] for tau=0..127 (125..127 zero). One block per chunk-col.
// ---------------------------------------------------------------------------
__global__ __launch_bounds__(256) void lnU_kernel(
    float* __restrict__ stream, _Float16* __restrict__ U,
    const float* __restrict__ g, const float* __restrict__ b) {
  __shared__ unsigned short Ut[128][260];   // [tau][h], padded stride
  int col = blockIdx.x;
  int wave = threadIdx.x >> 6, lane = threadIdx.x & 63;
  // zero pad rows tau=125..127
  for (int idx = threadIdx.x; idx < 3 * 260; idx += 256) {
    int r = idx / 260;
    Ut[125 + r][idx - r * 260] = 0;
  }
  float4 gg = ((const float4*)g)[lane];
  float4 bb = ((const float4*)b)[lane];
  size_t base = (size_t)col * LC * HH;
  for (int it = 0; it < 32; it++) {
    int tau = it * 4 + wave;
    if (tau < LC) {
      float4 v = ((const float4*)(stream + base + (size_t)tau * HH))[lane];
      float s = v.x + v.y + v.z + v.w;
      float q = v.x * v.x + v.y * v.y + v.z * v.z + v.w * v.w;
#pragma unroll
      for (int m = 1; m < 64; m <<= 1) { s += __shfl_xor(s, m); q += __shfl_xor(q, m); }
      float mean = s * (1.0f / HH);
      float var = q * (1.0f / HH) - mean * mean;
      float rstd = rsqrtf(var + 1e-5f);
      float4 o;
      o.x = (v.x - mean) * rstd * gg.x + bb.x;
      o.y = (v.y - mean) * rstd * gg.y + bb.y;
      o.z = (v.z - mean) * rstd * gg.z + bb.z;
      o.w = (v.w - mean) * rstd * gg.w + bb.w;
      ((float4*)(stream + base + (size_t)tau * HH))[lane] = o;  // residual = z, in place
      uint2 p;
      p.x = pk2h(o.x, o.y);
      p.y = pk2h(o.z, o.w);
      *(uint2*)&Ut[tau][4 * lane] = p;
    }
  }
  __syncthreads();
  // export transposed: per h, 64 u32 words (128 tau)
  for (int rep = 0; rep < 8; rep++) {
    int linear = rep * 256 + threadIdx.x;
    int h = linear >> 3, ub = linear & 7;
    unsigned* dst = (unsigned*)(U + ((size_t)h * COLS + col) * KU);
#pragma unroll
    for (int s2 = 0; s2 < 8; s2++) {
      int u = ub + s2 * 8;
      unsigned val = (unsigned)Ut[2 * u][h] | ((unsigned)Ut[2 * u + 1][h] << 16);
      dst[u] = val;
    }
  }
}

// ---------------------------------------------------------------------------
// gemmA: per h, P[n2=64][col=640] = V[h](64x128) @ U[h](128 x col) -> chunk states
// Block: one h x 64-col tile. Output written transposed: P[h][col][n2] (f32).
// ---------------------------------------------------------------------------
__global__ __launch_bounds__(256) void gemmA_kernel(
    const _Float16* __restrict__ V, const _Float16* __restrict__ U,
    float* __restrict__ P) {
  __shared__ _Float16 As[64 * 72];
  __shared__ _Float16 Bs[64 * 72];
  int h = blockIdx.x, c0 = blockIdx.y * 64;
  int t = threadIdx.x;
  int w = t >> 6, lane = t & 63, lr = lane & 15, quad = lane >> 4;
  int mh = w & 1, nh = w >> 1;
  f32x4 acc[2][2];
#pragma unroll
  for (int i = 0; i < 2; i++)
#pragma unroll
    for (int j = 0; j < 2; j++) acc[i][j] = (f32x4)(0.0f);

  for (int kt = 0; kt < 128; kt += 64) {
#pragma unroll
    for (int i = 0; i < 2; i++) {
      int idx = t + 256 * i;
      int m = idx >> 3, q = idx & 7;
      *(uint4*)&As[m * 72 + q * 8] =
          *(const uint4*)(V + ((size_t)h * 64 + m) * 128 + kt + q * 8);
      *(uint4*)&Bs[m * 72 + q * 8] =
          *(const uint4*)(U + ((size_t)h * COLS + c0 + m) * KU + kt + q * 8);
    }
    __syncthreads();
#pragma unroll
    for (int ks = 0; ks < 2; ks++) {
      f16x8 af[2], bf[2];
#pragma unroll
      for (int i = 0; i < 2; i++)
        af[i] = *(const f16x8*)&As[(mh * 32 + i * 16 + lr) * 72 + ks * 32 + quad * 8];
#pragma unroll
      for (int j = 0; j < 2; j++)
        bf[j] = *(const f16x8*)&Bs[(nh * 32 + j * 16 + lr) * 72 + ks * 32 + quad * 8];
#pragma unroll
      for (int i = 0; i < 2; i++)
#pragma unroll
        for (int j = 0; j < 2; j++)
          acc[i][j] = __builtin_amdgcn_mfma_f32_16x16x32_f16(af[i], bf[j], acc[i][j], 0, 0, 0);
    }
    __syncthreads();
  }
#pragma unroll
  for (int i = 0; i < 2; i++) {
#pragma unroll
    for (int j = 0; j < 2; j++) {
      int n2 = mh * 32 + i * 16 + quad * 4;          // + r contiguous
      int col = c0 + nh * 32 + j * 16 + lr;
      *(f32x4*)(P + ((size_t)h * COLS + col) * 64 + n2) = acc[i][j];
    }
  }
}

// ---------------------------------------------------------------------------
// combine: serial scan over chunks per (b,h,n): carry' = w^125*carry + P[c].
// Writes exclusive-prefix carry (fp16) into Ubig[h][col][128+n2].
// ---------------------------------------------------------------------------
__global__ __launch_bounds__(256) void combine_kernel(
    const float* __restrict__ P, _Float16* __restrict__ U,
    const float* __restrict__ WLc) {
  int h = blockIdx.x >> 1;
  int bh = blockIdx.x & 1;
  int n = threadIdx.x & 31;
  int b = bh * 8 + (threadIdx.x >> 5);
  float wre = WLc[h * 64 + 2 * n], wim = WLc[h * 64 + 2 * n + 1];
  const float* p = P + ((size_t)h * COLS + (size_t)b * NCH) * 64 + 2 * n;
  _Float16* u = U + ((size_t)h * COLS + (size_t)b * NCH) * KU + 128 + 2 * n;
  float cre = 0.0f, cim = 0.0f;
#pragma unroll 4
  for (int c = 0; c < NCH; c++) {
    float2 v = *(const float2*)(p + (size_t)c * 64);
    *(unsigned*)(u + (size_t)c * KU) = pk2h(cre, cim);
    float nre = fmaf(wre, cre, v.x) - wim * cim;
    float nim = fmaf(wre, cim, v.y) + wim * cre;
    cre = nre; cim = nim;
  }
}

// ---------------------------------------------------------------------------
// gemmC: per h, Y[t=128][col=640] = Tc[h](128x192) @ [u; s0](192 x col),
// fused GELU, output fp16 to Yt[h][col][t] (4 consecutive t per lane -> 8B st).
// ---------------------------------------------------------------------------
__global__ __launch_bounds__(256) void gemmC_kernel(
    const _Float16* __restrict__ Tc, const _Float16* __restrict__ U,
    _Float16* __restrict__ Yt) {
  __shared__ _Float16 As[128 * 72];
  __shared__ _Float16 Bs[64 * 72];
  int h = blockIdx.x, c0 = blockIdx.y * 64;
  int t = threadIdx.x;
  int w = t >> 6, lane = t & 63, lr = lane & 15, quad = lane >> 4;
  f32x4 acc[2][4];
#pragma unroll
  for (int i = 0; i < 2; i++)
#pragma unroll
    for (int j = 0; j < 4; j++) acc[i][j] = (f32x4)(0.0f);

  for (int kt = 0; kt < KU; kt += 64) {
#pragma unroll
    for (int i = 0; i < 4; i++) {
      int idx = t + 256 * i;
      int m = idx >> 3, q = idx & 7;
      *(uint4*)&As[m * 72 + q * 8] =
          *(const uint4*)(Tc + ((size_t)h * 128 + m) * KU + kt + q * 8);
    }
#pragma unroll
    for (int i = 0; i < 2; i++) {
      int idx = t + 256 * i;
      int jj = idx >> 3, q = idx & 7;
      *(uint4*)&Bs[jj * 72 + q * 8] =
          *(const uint4*)(U + ((size_t)h * COLS + c0 + jj) * KU + kt + q * 8);
    }
    __syncthreads();
#pragma unroll
    for (int ks = 0; ks < 2; ks++) {
      f16x8 af[2], bf[4];
#pragma unroll
      for (int i = 0; i < 2; i++)
        af[i] = *(const f16x8*)&As[(w * 32 + i * 16 + lr) * 72 + ks * 32 + quad * 8];
#pragma unroll
      for (int j = 0; j < 4; j++)
        bf[j] = *(const f16x8*)&Bs[(j * 16 + lr) * 72 + ks * 32 + quad * 8];
#pragma unroll
      for (int i = 0; i < 2; i++)
#pragma unroll
        for (int j = 0; j < 4; j++)
          acc[i][j] = __builtin_amdgcn_mfma_f32_16x16x32_f16(af[i], bf[j], acc[i][j], 0, 0, 0);
    }
    __syncthreads();
  }
#pragma unroll
  for (int i = 0; i < 2; i++) {
#pragma unroll
    for (int j = 0; j < 4; j++) {
      int tb = w * 32 + i * 16 + quad * 4;
      int col = c0 + j * 16 + lr;
      f32x4 a = acc[i][j];
      uint2 r;
      r.x = pk2h(fast_gelu(a[0]), fast_gelu(a[1]));
      r.y = pk2h(fast_gelu(a[2]), fast_gelu(a[3]));
      *(uint2*)(Yt + ((size_t)h * COLS + col) * 128 + tb) = r;
    }
  }
}

// ---------------------------------------------------------------------------
// Yt[h][col][128] -> row-major Y[row=col*125+t][h] (fp16), LDS-tiled transpose.
// Block: (col, h-half of 128).
// ---------------------------------------------------------------------------
__global__ __launch_bounds__(256) void ytr_kernel(
    const _Float16* __restrict__ Yt, _Float16* __restrict__ Y) {
  __shared__ unsigned short Yl[128][136];
  int col = blockIdx.x, hh = blockIdx.y;
#pragma unroll
  for (int rep = 0; rep < 8; rep++) {
    int cid = rep * 256 + threadIdx.x;
    int hl = cid >> 4, q = cid & 15;
    *(uint4*)&Yl[hl][q * 8] =
        *(const uint4*)(Yt + ((size_t)(hh * 128 + hl) * COLS + col) * 128 + q * 8);
  }
  __syncthreads();
#pragma unroll
  for (int rep = 0; rep < 8; rep++) {
    int sid = rep * 256 + threadIdx.x;
    int tl = sid >> 4, uq = sid & 15;
    if (tl < LC) {
      uint4 r;
      unsigned v[4];
#pragma unroll
      for (int k = 0; k < 4; k++)
        v[k] = (unsigned)Yl[uq * 8 + 2 * k][tl] | ((unsigned)Yl[uq * 8 + 2 * k + 1][tl] << 16);
      r.x = v[0]; r.y = v[1]; r.z = v[2]; r.w = v[3];
      *(uint4*)(Y + ((size_t)col * LC + tl) * HH + hh * 128 + uq * 8) = r;
    }
  }
}

// ---------------------------------------------------------------------------
// GLU FFN via fp16 MFMA (unchanged structure): out = G1*sigmoid(G2) + Z,
// in-place on the residual stream (Z == X).
// ---------------------------------------------------------------------------
__global__ __launch_bounds__(256) void gemm_glu_mfma(
    const _Float16* __restrict__ Y, const _Float16* __restrict__ Wt,
    const float* __restrict__ bg, const float* __restrict__ Z,
    float* __restrict__ X) {
  __shared__ _Float16 As[128 * 72];
  __shared__ _Float16 Bs[128 * 72];
  int t = threadIdx.x;
  int r0 = blockIdx.x * 128, c0 = blockIdx.y * 64;
  int w = t >> 6, lane = t & 63;
  int lr = lane & 15, quad = lane >> 4;
  int rh = w & 1, ch = w >> 1;
  f32x4 acc[4][4];
#pragma unroll
  for (int i = 0; i < 4; i++)
#pragma unroll
    for (int j = 0; j < 4; j++) acc[i][j] = (f32x4)(0.0f);

  int jb[4] = {ch * 32, ch * 32 + 16, 64 + ch * 32, 80 + ch * 32};

  for (int kt = 0; kt < HH; kt += 64) {
#pragma unroll
    for (int i = 0; i < 4; i++) {
      int idx = t + 256 * i;
      int m = idx >> 3, q = idx & 7;
      uint4 v = *(const uint4*)(Y + (size_t)(r0 + m) * HH + kt + q * 8);
      *(uint4*)&As[m * 72 + q * 8] = v;
    }
#pragma unroll
    for (int i = 0; i < 4; i++) {
      int idx = t + 256 * i;
      int jj = idx >> 3, q = idx & 7;
      int col = (jj < 64) ? (c0 + jj) : (192 + c0 + jj);
      uint4 v = *(const uint4*)(Wt + (size_t)col * HH + kt + q * 8);
      *(uint4*)&Bs[jj * 72 + q * 8] = v;
    }
    __syncthreads();
#pragma unroll
    for (int ks = 0; ks < 2; ks++) {
      f16x8 af[4], bf[4];
#pragma unroll
      for (int i = 0; i < 4; i++)
        af[i] = *(const f16x8*)&As[(rh * 64 + i * 16 + lr) * 72 + ks * 32 + quad * 8];
#pragma unroll
      for (int j = 0; j < 4; j++)
        bf[j] = *(const f16x8*)&Bs[(jb[j] + lr) * 72 + ks * 32 + quad * 8];
#pragma unroll
      for (int i = 0; i < 4; i++)
#pragma unroll
        for (int j = 0; j < 4; j++)
          acc[i][j] = __builtin_amdgcn_mfma_f32_16x16x32_f16(af[i], bf[j], acc[i][j], 0, 0, 0);
    }
    __syncthreads();
  }
#pragma unroll
  for (int i = 0; i < 4; i++) {
#pragma unroll
    for (int r = 0; r < 4; r++) {
      int row = r0 + rh * 64 + i * 16 + quad * 4 + r;
#pragma unroll
      for (int jp = 0; jp < 2; jp++) {
        int h = c0 + ch * 32 + jp * 16 + lr;
        float g1 = acc[i][jp][r] + bg[h];
        float g2 = acc[i][jp + 2][r] + bg[256 + h];
        float sig = __builtin_amdgcn_rcpf(1.0f + __expf(-g2));
        X[(size_t)row * HH + h] = fmaf(g1, sig, Z[(size_t)row * HH + h]);
      }
    }
  }
}

// ---------------------------------------------------------------------------
extern "C" void kernel_launch(void* const* d_in, const int* in_sizes, int n_in,
                              void* d_out, int out_size, void* d_ws, size_t ws_size,
                              hipStream_t stream) {
  const float* x      = (const float*)d_in[0];
  const float* Win    = (const float*)d_in[1];
  const float* bin    = (const float*)d_in[2];
  const float* ln_g   = (const float*)d_in[3];
  const float* ln_b   = (const float*)d_in[4];
  const float* log_dt = (const float*)d_in[5];
  const float* logA   = (const float*)d_in[6];
  const float* A_im   = (const float*)d_in[7];
  const float* Cp     = (const float*)d_in[8];
  const float* Dv     = (const float*)d_in[9];
  const float* Wglu   = (const float*)d_in[10];
  const float* bglu   = (const float*)d_in[11];
  const float* fn_g   = (const float*)d_in[12];
  const float* fn_b   = (const float*)d_in[13];
  float* out = (float*)d_out;
  float* ws = (float*)d_ws;

  // Workspace layout (float units), total 51,167,232 floats = 204.7 MB
  float* Xs = ws;                                     // residual stream, 20,480,000
  float* P  = Xs + (size_t)NROWS * HH;                // 10,485,760 (also hosts Yt fp16)
  _Float16* Tc = (_Float16*)(P + (size_t)HH * COLS * 64);       // 6,291,456 fp16
  _Float16* V  = Tc + (size_t)HH * 128 * KU;                    // 2,097,152 fp16
  _Float16* U  = V + (size_t)HH * 64 * 128;                     // 31,457,280 fp16
  _Float16* Wt = U + (size_t)HH * COLS * KU;                    // 524,288 fp16
  float* WLc = (float*)(Wt + (size_t)NLAYER * 512 * HH);        // 16,384 f32
  _Float16* Yt = (_Float16*)P;                        // fp16 alias of P (disjoint lifetime)
  _Float16* Y  = (_Float16*)d_out;                    // row-major activations for GLU

  wt_kernel<<<(NLAYER * 512) / 256, 256, 0, stream>>>(Wglu, Wt);
  proj_kernel<<<2048, 256, 0, stream>>>(x, Win, bin, Xs);

  for (int l = 0; l < NLAYER; l++) {
    paramT_kernel<<<HH, 128, 0, stream>>>(log_dt, logA, A_im, Cp, Dv, l, Tc, V, WLc);
    lnU_kernel<<<COLS, 256, 0, stream>>>(Xs, U, ln_g + l * HH, ln_b + l * HH);
    gemmA_kernel<<<dim3(HH, COLS / 64), 256, 0, stream>>>(V, U, P);
    combine_kernel<<<HH * 2, 256, 0, stream>>>(P, U, WLc);
    gemmC_kernel<<<dim3(HH, COLS / 64), 256, 0, stream>>>(Tc, U, Yt);
    ytr_kernel<<<dim3(COLS, 2), 256, 0, stream>>>(Yt, Y);
    gemm_glu_mfma<<<dim3(NROWS / 128, 4), 256, 0, stream>>>(
        Y, Wt + (size_t)l * 512 * HH, bglu + (size_t)l * 2 * HH, Xs, Xs);
  }
  ln_kernel<<<NROWS / 4, 256, 0, stream>>>(Xs, out, fn_g, fn_b);
}